// Round 1
// baseline (285.391 us; speedup 1.0000x reference)
//
#include <hip/hip_runtime.h>
#include <hip/hip_bf16.h>

// Problem: out[m,e] = sum_f relu( sum_q cos(x[m,q])cos(theta[q]) w1[f,q] ) * w2[e,f]
// M = 16384 (B*S), E = 1024, F = 4096, NQ = 8. All inputs fp32, output fp32.
// Strategy: precompute A = relu(qv @ w1^T) as bf16 in d_ws, then bf16 MFMA GEMM
// out = A @ w2^T (w2 converted fp32->bf16 in-kernel during staging).

#define M_TOTAL 16384
#define E_DIM 1024
#define F_DIM 4096
#define NQ 8

typedef __attribute__((ext_vector_type(8))) short bf16x8;
typedef __attribute__((ext_vector_type(8))) unsigned short ushort8;
typedef __attribute__((ext_vector_type(4))) float f32x4;

__device__ __forceinline__ unsigned short f2bf(float f) {
  // round-to-nearest-even fp32 -> bf16 (inputs are finite; no NaN handling needed)
  union { float f; unsigned u; } c; c.f = f;
  unsigned u = c.u + (0x7fffu + ((c.u >> 16) & 1u));
  return (unsigned short)(u >> 16);
}

// ---------------------------------------------------------------------------
// Kernel 1: A[m][f] = relu( sum_q qv[m][q] * w1[f][q] ), bf16, A is [rows][F_DIM]
// block = 256 threads, 32 m-rows per block. w1 is 128 KB -> L2-resident.
// Each thread owns f-octets {t, t+256}; stores are 16 B/lane fully coalesced.
// ---------------------------------------------------------------------------
__global__ __launch_bounds__(256) void qrelu_kernel(
    const float* __restrict__ x, const float* __restrict__ theta,
    const float* __restrict__ w1, unsigned short* __restrict__ A, int m_base) {
  __shared__ float qv[32][NQ];
  const int t = threadIdx.x;
  const int m0 = m_base + blockIdx.x * 32;
  {
    const int ml = t >> 3, q = t & 7;
    float xv = x[(size_t)(m0 + ml) * 1024 + q];
    qv[ml][q] = cosf(xv) * cosf(theta[q]);
  }
  __syncthreads();

  for (int oi = 0; oi < 2; ++oi) {
    const int o = t + oi * 256;  // f-octet index 0..511  (f = o*8)
    float w[64];                 // w1[o*8 + j][q], 64 contiguous floats
#pragma unroll
    for (int i = 0; i < 16; ++i)
      *(float4*)&w[i * 4] = *(const float4*)&w1[o * 64 + i * 4];
    for (int ml = 0; ml < 32; ++ml) {
      ushort8 pk;
#pragma unroll
      for (int j = 0; j < 8; ++j) {
        float s = 0.f;
#pragma unroll
        for (int q = 0; q < NQ; ++q) s = fmaf(qv[ml][q], w[j * 8 + q], s);
        pk[j] = f2bf(s > 0.f ? s : 0.f);
      }
      *(ushort8*)&A[(size_t)(m0 - m_base + ml) * F_DIM + o * 8] = pk;
    }
  }
}

// ---------------------------------------------------------------------------
// Kernel 2: out[m][e] = sum_f A[m][f] * w2[e][f]   (bf16 MFMA, fp32 accum)
// 256x256 tile, BK=64, 512 threads = 8 waves (2x4), wave tile 128x64.
// 2-phase: stage(next) -> compute(cur) -> one barrier per K-tile.
// A staged via global_load_lds (16B); B staged fp32->bf16 via registers.
// LDS = 2*(32KB A + 32KB B) = 128 KiB -> 1 block/CU.
// ---------------------------------------------------------------------------
__global__ __launch_bounds__(512, 2) void gemm_kernel(
    const unsigned short* __restrict__ Abf, const float* __restrict__ w2,
    float* __restrict__ out, int m_base) {
  __shared__ __align__(16) unsigned short As[2][256 * 64];
  __shared__ __align__(16) unsigned short Bs[2][256 * 64];
  const int tid = threadIdx.x;
  const int lane = tid & 63;
  const int wid = tid >> 6;
  const int wr = wid >> 2;  // 0..1 : m-half (128 rows)
  const int wc = wid & 3;   // 0..3 : n-quarter (64 cols)
  const int mb = blockIdx.x >> 2;
  const int n0 = (blockIdx.x & 3) * 256;
  const unsigned short* Ag = Abf + (size_t)mb * 256 * F_DIM;

  f32x4 acc[8][4] = {};

  auto stage = [&](int buf, int kt) {
    // --- A tile [256 m][64 k] bf16: 4 x (512 threads x 16 B) = 32 KB ---
#pragma unroll
    for (int c = 0; c < 4; ++c) {
      const unsigned short* g =
          Ag + (size_t)(c * 64 + (tid >> 3)) * F_DIM + kt * 64 + (tid & 7) * 8;
      unsigned short* l = &As[buf][c * 4096 + wid * 512];  // wave-uniform base
      __builtin_amdgcn_global_load_lds(
          (const __attribute__((address_space(1))) void*)g,
          (__attribute__((address_space(3))) void*)l, 16, 0, 0);
    }
    // --- B tile [256 n][64 k]: w2 fp32 -> bf16, reg-staged ---
    const float* g = w2 + ((size_t)(n0 + (tid >> 1)) << 12) + kt * 64 + (tid & 1) * 32;
    unsigned short* l = &Bs[buf][(tid >> 1) * 64 + (tid & 1) * 32];
#pragma unroll
    for (int h = 0; h < 2; ++h) {
      float v[16];
#pragma unroll
      for (int i = 0; i < 4; ++i)
        *(float4*)&v[i * 4] = *(const float4*)&g[h * 16 + i * 4];
      ushort8 p0, p1;
#pragma unroll
      for (int j = 0; j < 8; ++j) { p0[j] = f2bf(v[j]); p1[j] = f2bf(v[8 + j]); }
      *(ushort8*)&l[h * 16] = p0;
      *(ushort8*)&l[h * 16 + 8] = p1;
    }
  };

  auto compute = [&](int buf) {
#pragma unroll
    for (int ks = 0; ks < 2; ++ks) {
      const int ko = ks * 32 + (lane >> 4) * 8;  // k element offset for this lane
      bf16x8 afr[8], bfr[4];
#pragma unroll
      for (int mt = 0; mt < 8; ++mt)
        afr[mt] = *(const bf16x8*)&As[buf][(wr * 128 + mt * 16 + (lane & 15)) * 64 + ko];
#pragma unroll
      for (int nt = 0; nt < 4; ++nt)
        bfr[nt] = *(const bf16x8*)&Bs[buf][(wc * 64 + nt * 16 + (lane & 15)) * 64 + ko];
#pragma unroll
      for (int mt = 0; mt < 8; ++mt)
#pragma unroll
        for (int nt = 0; nt < 4; ++nt)
          acc[mt][nt] = __builtin_amdgcn_mfma_f32_16x16x32_bf16(
              afr[mt], bfr[nt], acc[mt][nt], 0, 0, 0);
    }
  };

  stage(0, 0);
  __syncthreads();
  int buf = 0;
  for (int kt = 0; kt < F_DIM / 64; ++kt) {
    if (kt < F_DIM / 64 - 1) stage(buf ^ 1, kt + 1);
    compute(buf);
    __syncthreads();
    buf ^= 1;
  }

  // Epilogue: C/D layout col = lane&15, row = (lane>>4)*4 + r  [m89-verified]
  const int cl = lane & 15, rg = lane >> 4;
  const size_t orow0 = (size_t)m_base + (size_t)mb * 256 + (size_t)wr * 128;
  float* ob = out + orow0 * E_DIM + n0 + wc * 64 + cl;
#pragma unroll
  for (int mt = 0; mt < 8; ++mt)
#pragma unroll
    for (int r = 0; r < 4; ++r) {
      float* orow = ob + (size_t)(mt * 16 + rg * 4 + r) * E_DIM;
#pragma unroll
      for (int nt = 0; nt < 4; ++nt) orow[nt * 16] = acc[mt][nt][r];
    }
}

// ---------------------------------------------------------------------------
extern "C" void kernel_launch(void* const* d_in, const int* in_sizes, int n_in,
                              void* d_out, int out_size, void* d_ws, size_t ws_size,
                              hipStream_t stream) {
  const float* x = (const float*)d_in[0];
  const float* theta = (const float*)d_in[1];
  const float* w1 = (const float*)d_in[2];
  const float* w2 = (const float*)d_in[3];
  float* out = (float*)d_out;
  unsigned short* A = (unsigned short*)d_ws;

  // Chunk M by workspace capacity (A chunk = rows * F_DIM * 2 bytes).
  // Normally ws >= 128 MiB -> single chunk of 16384 rows.
  size_t maxrows = ws_size / ((size_t)F_DIM * 2);
  int Mc = (int)((maxrows / 256) * 256);
  if (Mc > M_TOTAL) Mc = M_TOTAL;
  if (Mc < 256) Mc = 256;  // ws is expected to be at least 2 MiB

  for (int mb = 0; mb < M_TOTAL; mb += Mc) {
    int rows = M_TOTAL - mb < Mc ? M_TOTAL - mb : Mc;
    qrelu_kernel<<<rows / 32, 256, 0, stream>>>(x, theta, w1, A, mb);
    gemm_kernel<<<(rows / 256) * 4, 512, 0, stream>>>(A, w2, out, mb);
  }
}

// Round 2
// 155.478 us; speedup vs baseline: 1.8356x; 1.8356x over previous
//
#include <hip/hip_runtime.h>
#include <hip/hip_bf16.h>

// out[m,e] = sum_f relu( sum_q cos(x[m,q])cos(theta[q]) w1[f,q] ) * w2[e,f]
// M=16384, E=1024, F=4096. Pipeline:
//   1) w2cvt: w2 fp32 -> bf16 once into ws
//   2) qrelu: A = relu(qv @ w1^T) bf16 into ws
//   3) gemm8: out = A @ w2bf^T -- 256x256 tile, BK=64, 8 waves, 8-phase
//      schedule (T3+T4 counted vmcnt), LDS XOR-swizzle (T2), setprio (T5),
//      bijective XCD swizzle (T1). Both operands via global_load_lds(16B)
//      with pre-swizzled global source (rule #21).

#define M_TOTAL 16384
#define E_DIM 1024
#define F_DIM 4096
#define NQ 8

typedef __attribute__((ext_vector_type(8))) short bf16x8;
typedef __attribute__((ext_vector_type(8))) unsigned short ushort8;
typedef __attribute__((ext_vector_type(4))) float f32x4;

__device__ __forceinline__ unsigned short f2bf(float f) {
  union { float f; unsigned u; } c; c.f = f;
  unsigned u = c.u + (0x7fffu + ((c.u >> 16) & 1u));
  return (unsigned short)(u >> 16);
}

// ---------------------------------------------------------------------------
__global__ __launch_bounds__(256) void w2cvt_kernel(
    const float* __restrict__ w2, unsigned short* __restrict__ w2bf) {
  size_t i = ((size_t)blockIdx.x * 256 + threadIdx.x) * 8;
  float v[8];
  *(float4*)&v[0] = *(const float4*)&w2[i];
  *(float4*)&v[4] = *(const float4*)&w2[i + 4];
  ushort8 p;
#pragma unroll
  for (int j = 0; j < 8; ++j) p[j] = f2bf(v[j]);
  *(ushort8*)&w2bf[i] = p;
}

// ---------------------------------------------------------------------------
__global__ __launch_bounds__(256) void qrelu_kernel(
    const float* __restrict__ x, const float* __restrict__ theta,
    const float* __restrict__ w1, unsigned short* __restrict__ A, int m_base) {
  __shared__ float qv[32][NQ];
  const int t = threadIdx.x;
  const int m0 = m_base + blockIdx.x * 32;
  {
    const int ml = t >> 3, q = t & 7;
    float xv = x[(size_t)(m0 + ml) * 1024 + q];
    qv[ml][q] = cosf(xv) * cosf(theta[q]);
  }
  __syncthreads();

  for (int oi = 0; oi < 2; ++oi) {
    const int o = t + oi * 256;  // f-octet index 0..511
    float w[64];
#pragma unroll
    for (int i = 0; i < 16; ++i)
      *(float4*)&w[i * 4] = *(const float4*)&w1[o * 64 + i * 4];
    for (int ml = 0; ml < 32; ++ml) {
      ushort8 pk;
#pragma unroll
      for (int j = 0; j < 8; ++j) {
        float s = 0.f;
#pragma unroll
        for (int q = 0; q < NQ; ++q) s = fmaf(qv[ml][q], w[j * 8 + q], s);
        pk[j] = f2bf(s > 0.f ? s : 0.f);
      }
      *(ushort8*)&A[(size_t)(m0 - m_base + ml) * F_DIM + o * 8] = pk;
    }
  }
}

// ---------------------------------------------------------------------------
// GEMM: BM=BN=256, BK=64, 512 thr = 8 waves (2m x 4n), wave tile 128x64.
// LDS: As/Bs [2 dbuf][2 half][128*64] bf16 = 64KB + 64KB = 128 KiB.
// Swizzle: data for (row, 16B-chunk c) lives at physical chunk c ^ (row&7).
// 8 phases per iteration (2 K-tiles): quadrant order (ms,ns) =
// (0,0)(0,1)(1,1)(1,0) reuses B-low across phases 1&4.
// Stage slots: p0/p1: A halves of kt=2i+1 (buf1); p2/p3: B halves kt=2i+2;
// p4/p5: A halves kt=2i+2 (buf0); p6/p7: B halves kt=2i+3 (buf1).
// vmcnt(4) at p3 and p7 (2 loads/half-tile x 2 half-tiles in flight).
// ---------------------------------------------------------------------------
#define MFMA_PHASE(ms, ns, B) do { \
  __builtin_amdgcn_s_barrier(); \
  asm volatile("s_waitcnt lgkmcnt(0)" ::: "memory"); \
  __builtin_amdgcn_sched_barrier(0); \
  __builtin_amdgcn_s_setprio(1); \
  _Pragma("unroll") \
  for (int mt2 = 0; mt2 < 4; ++mt2) { \
    _Pragma("unroll") \
    for (int nt2 = 0; nt2 < 2; ++nt2) { \
      _Pragma("unroll") \
      for (int kk = 0; kk < 2; ++kk) { \
        acc[(ms) * 4 + mt2][(ns) * 2 + nt2] = \
            __builtin_amdgcn_mfma_f32_16x16x32_bf16( \
                af[mt2][kk], B[nt2][kk], acc[(ms) * 4 + mt2][(ns) * 2 + nt2], \
                0, 0, 0); \
      } } } \
  __builtin_amdgcn_s_setprio(0); \
  __builtin_amdgcn_s_barrier(); \
} while (0)

__global__ __launch_bounds__(512, 2) void gemm8_kernel(
    const unsigned short* __restrict__ Abf, const unsigned short* __restrict__ w2bf,
    float* __restrict__ out, int m_base) {
  __shared__ __align__(16) unsigned short As[2][2][128 * 64];
  __shared__ __align__(16) unsigned short Bs[2][2][128 * 64];

  const int tid = threadIdx.x;
  const int lane = tid & 63;
  const int wid = tid >> 6;
  const int wr = wid >> 2;  // m-half of block
  const int wc = wid & 3;   // n-quarter of block

  // T1: bijective XCD-chunked swizzle (m204); nb fastest within chunk.
  const int nwg = gridDim.x;
  const int bid = blockIdx.x;
  const int qq = nwg >> 3, rr = nwg & 7;
  const int xcd = bid & 7, sub = bid >> 3;
  const int wgid =
      (xcd < rr ? xcd * (qq + 1) : rr * (qq + 1) + (xcd - rr) * qq) + sub;
  const int mb = wgid >> 2;
  const int nb = wgid & 3;

  const unsigned short* Ag = Abf + (size_t)mb * 256 * F_DIM;
  const unsigned short* Bg = w2bf + (size_t)nb * 256 * F_DIM;

  f32x4 acc[8][4] = {};
  bf16x8 af[4][2], blo[2][2], bhi[2][2];

  // stage one half-tile (128 rows x 64 k) via 2 x global_load_lds(16B).
  // LDS dest is linear (wave-uniform base + lane*16); the swizzle is applied
  // by permuting the global SOURCE chunk: c = (tid&7) ^ ((tid>>3)&7).
  auto stA = [&](int buf, int half, int kt) {
#pragma unroll
    for (int rnd = 0; rnd < 2; ++rnd) {
      const int row = rnd * 64 + (tid >> 3);
      const int c = (tid & 7) ^ ((tid >> 3) & 7);
      const unsigned short* g =
          Ag + (size_t)(half * 128 + row) * F_DIM + kt * 64 + c * 8;
      __builtin_amdgcn_global_load_lds(
          (const __attribute__((address_space(1))) void*)g,
          (__attribute__((address_space(3))) void*)&As[buf][half]
                                                      [rnd * 4096 + wid * 512],
          16, 0, 0);
    }
  };
  auto stB = [&](int buf, int half, int kt) {
#pragma unroll
    for (int rnd = 0; rnd < 2; ++rnd) {
      const int row = rnd * 64 + (tid >> 3);
      const int c = (tid & 7) ^ ((tid >> 3) & 7);
      const unsigned short* g =
          Bg + (size_t)(half * 128 + row) * F_DIM + kt * 64 + c * 8;
      __builtin_amdgcn_global_load_lds(
          (const __attribute__((address_space(1))) void*)g,
          (__attribute__((address_space(3))) void*)&Bs[buf][half]
                                                      [rnd * 4096 + wid * 512],
          16, 0, 0);
    }
  };

  // ds_read a register subtile; read-side swizzle matches (r&7 == lane&7).
  auto rdA = [&](int buf, int ms) {
#pragma unroll
    for (int mt2 = 0; mt2 < 4; ++mt2)
#pragma unroll
      for (int kk = 0; kk < 2; ++kk) {
        const int r = ms * 64 + mt2 * 16 + (lane & 15);
        const int c = (kk * 4 + (lane >> 4)) ^ (lane & 7);
        af[mt2][kk] = *(const bf16x8*)&As[buf][wr][r * 64 + c * 8];
      }
  };
  auto rdB = [&](int buf, int ns, bf16x8(&B)[2][2]) {
#pragma unroll
    for (int nt2 = 0; nt2 < 2; ++nt2)
#pragma unroll
      for (int kk = 0; kk < 2; ++kk) {
        const int rf = wc * 64 + ns * 32 + nt2 * 16 + (lane & 15);
        const int c = (kk * 4 + (lane >> 4)) ^ (lane & 7);
        B[nt2][kk] = *(const bf16x8*)&Bs[buf][rf >> 7][(rf & 127) * 64 + c * 8];
      }
  };

  // --- prologue: kt0 all 4 half-tiles + kt1 B halves; land kt0. ---
  stB(0, 0, 0); stB(0, 1, 0); stA(0, 0, 0); stA(0, 1, 0);
  stB(1, 0, 1); stB(1, 1, 1);
  asm volatile("s_waitcnt vmcnt(4)" ::: "memory");
  __builtin_amdgcn_s_barrier();

#pragma unroll 1
  for (int it = 0; it < F_DIM / 128; ++it) {
    const bool last = (it == F_DIM / 128 - 1);
    const int k0 = 2 * it;
    // p0: quadrant (0,0) of buf0
    rdA(0, 0); rdB(0, 0, blo);
    stA(1, 0, k0 + 1);
    MFMA_PHASE(0, 0, blo);
    // p1: (0,1)
    rdB(0, 1, bhi);
    stA(1, 1, k0 + 1);
    MFMA_PHASE(0, 1, bhi);
    // p2: (1,1)
    rdA(0, 1);
    if (!last) stB(0, 0, k0 + 2);
    MFMA_PHASE(1, 1, bhi);
    // p3: (1,0) -- vmcnt gate for buf1 reads at p4
    if (!last) {
      stB(0, 1, k0 + 2);
      asm volatile("s_waitcnt vmcnt(4)" ::: "memory");
    } else {
      asm volatile("s_waitcnt vmcnt(0)" ::: "memory");
    }
    MFMA_PHASE(1, 0, blo);
    // p4: quadrant (0,0) of buf1
    rdA(1, 0); rdB(1, 0, blo);
    if (!last) stA(0, 0, k0 + 2);
    MFMA_PHASE(0, 0, blo);
    // p5: (0,1)
    rdB(1, 1, bhi);
    if (!last) stA(0, 1, k0 + 2);
    MFMA_PHASE(0, 1, bhi);
    // p6: (1,1)
    rdA(1, 1);
    if (!last) stB(1, 0, k0 + 3);
    MFMA_PHASE(1, 1, bhi);
    // p7: (1,0) -- vmcnt gate for buf0 reads at next p0
    if (!last) {
      stB(1, 1, k0 + 3);
      asm volatile("s_waitcnt vmcnt(4)" ::: "memory");
    }
    MFMA_PHASE(1, 0, blo);
  }

  // Epilogue: C/D layout col = lane&15, row = (lane>>4)*4 + r [m89-verified]
  const int cl = lane & 15, rg = lane >> 4;
  float* ob = out + (size_t)(m_base + mb * 256 + wr * 128) * E_DIM + nb * 256 +
              wc * 64 + cl;
#pragma unroll
  for (int mt = 0; mt < 8; ++mt)
#pragma unroll
    for (int r = 0; r < 4; ++r) {
      float* orow = ob + (size_t)(mt * 16 + rg * 4 + r) * E_DIM;
#pragma unroll
      for (int nt = 0; nt < 4; ++nt) orow[nt * 16] = acc[mt][nt][r];
    }
}

// ---------------------------------------------------------------------------
extern "C" void kernel_launch(void* const* d_in, const int* in_sizes, int n_in,
                              void* d_out, int out_size, void* d_ws, size_t ws_size,
                              hipStream_t stream) {
  const float* x = (const float*)d_in[0];
  const float* theta = (const float*)d_in[1];
  const float* w1 = (const float*)d_in[2];
  const float* w2 = (const float*)d_in[3];
  float* out = (float*)d_out;

  unsigned short* w2bf = (unsigned short*)d_ws;           // 8 MiB
  unsigned short* A = w2bf + (size_t)E_DIM * F_DIM;       // rest of ws

  size_t abytes = ws_size - (size_t)E_DIM * F_DIM * 2;
  size_t maxrows = abytes / ((size_t)F_DIM * 2);
  int Mc = (int)((maxrows / 256) * 256);
  if (Mc > M_TOTAL) Mc = M_TOTAL;
  if (Mc < 256) Mc = 256;

  w2cvt_kernel<<<E_DIM * F_DIM / 2048, 256, 0, stream>>>(w2, w2bf);

  for (int mb = 0; mb < M_TOTAL; mb += Mc) {
    int rows = M_TOTAL - mb < Mc ? M_TOTAL - mb : Mc;
    qrelu_kernel<<<rows / 32, 256, 0, stream>>>(x, theta, w1, A, mb);
    gemm8_kernel<<<(rows / 256) * 4, 512, 0, stream>>>(A, w2bf, out, mb);
  }
}